// Round 1
// baseline (126.198 us; speedup 1.0000x reference)
//
#include <hip/hip_runtime.h>

#define H_IN 4096
#define W_IN 4096
#define KH 15
#define KW 15
#define OH (H_IN - KH + 1)   // 4082
#define OW (W_IN - KW + 1)   // 4082

#define TILE_X 128           // output tile width per block
#define TILE_Y 32            // output tile height per block
#define TX_PER 16            // outputs per thread along x
#define NTX (TILE_X / TX_PER)        // 8 threads in x
#define IN_W (TILE_X + KW - 1)       // 142 input cols needed
#define IN_H (TILE_Y + KH - 1)       // 46 input rows needed
#define LDS_STRIDE 148               // padded: mult of 4 (alignment), 148%32=20 (bank-friendly)
#define CHUNKS 36                    // float4 chunks staged per row (144 floats >= 142)

__global__ __launch_bounds__(256, 2)
void conv2d_direct_f32(const float* __restrict__ X,
                       const float* __restrict__ Wt,
                       const float* __restrict__ Bias,
                       float* __restrict__ Out)
{
    __shared__ float s_in[IN_H * LDS_STRIDE];
    __shared__ float s_w[KH * 16];          // weights, rows padded to 16

    const int tid = threadIdx.x;
    const int ox0 = blockIdx.x * TILE_X;
    const int oy0 = blockIdx.y * TILE_Y;

    // ---- stage weights (225 floats -> padded rows of 16) ----
    if (tid < KH * KW) {
        int r = tid / KW, c = tid % KW;
        s_w[r * 16 + c] = Wt[tid];
    }

    // ---- stage input tile: IN_H rows x 144 floats (36 float4/row) ----
    for (int i = tid; i < IN_H * CHUNKS; i += 256) {
        int r  = i / CHUNKS;
        int c4 = i % CHUNKS;
        int gy = oy0 + r;       if (gy > H_IN - 1) gy = H_IN - 1;
        int gx = ox0 + c4 * 4;
        float4 v;
        if (gx + 3 < W_IN) {
            v = *reinterpret_cast<const float4*>(&X[(size_t)gy * W_IN + gx]);
        } else {
            int x0 = min(gx + 0, W_IN - 1);
            int x1 = min(gx + 1, W_IN - 1);
            int x2 = min(gx + 2, W_IN - 1);
            int x3 = min(gx + 3, W_IN - 1);
            const float* rp = &X[(size_t)gy * W_IN];
            v.x = rp[x0]; v.y = rp[x1]; v.z = rp[x2]; v.w = rp[x3];
        }
        *reinterpret_cast<float4*>(&s_in[r * LDS_STRIDE + c4 * 4]) = v;
    }
    __syncthreads();

    const int tx = tid & (NTX - 1);     // 0..7
    const int ty = tid >> 3;            // 0..31
    const int lx = tx * TX_PER;         // strip start within tile (mult of 16 -> 64B aligned)

    float acc[TX_PER];
#pragma unroll
    for (int j = 0; j < TX_PER; ++j) acc[j] = 0.0f;

#pragma unroll 1
    for (int kh = 0; kh < KH; ++kh) {
        // sliding window: 32 floats from LDS row (ty+kh), 8 x ds_read_b128
        const float* rowp = &s_in[(ty + kh) * LDS_STRIDE + lx];
        float win[2 * TX_PER];
#pragma unroll
        for (int c = 0; c < 8; ++c) {
            float4 v = reinterpret_cast<const float4*>(rowp)[c];
            win[4 * c + 0] = v.x;
            win[4 * c + 1] = v.y;
            win[4 * c + 2] = v.z;
            win[4 * c + 3] = v.w;
        }
        // weight row: 16 floats (15 used), 4 x ds_read_b128, uniform -> broadcast
        float wr[16];
#pragma unroll
        for (int c = 0; c < 4; ++c) {
            float4 v = reinterpret_cast<const float4*>(&s_w[kh * 16])[c];
            wr[4 * c + 0] = v.x;
            wr[4 * c + 1] = v.y;
            wr[4 * c + 2] = v.z;
            wr[4 * c + 3] = v.w;
        }
#pragma unroll
        for (int kw = 0; kw < KW; ++kw) {
            float wv = wr[kw];
#pragma unroll
            for (int j = 0; j < TX_PER; ++j) {
                acc[j] = fmaf(win[j + kw], wv, acc[j]);
            }
        }
    }

    // ---- store ----
    const float b = Bias[0];
    const int orow  = oy0 + ty;
    const int ocol0 = ox0 + lx;
    if (orow < OH) {
        float* op = &Out[(size_t)orow * OW + ocol0];
        if (ocol0 + TX_PER <= OW) {
            // index (orow*4082 + ocol0) is always even -> 8B-aligned float2 stores
#pragma unroll
            for (int c = 0; c < 8; ++c) {
                float2 v;
                v.x = acc[2 * c + 0] + b;
                v.y = acc[2 * c + 1] + b;
                *reinterpret_cast<float2*>(&op[2 * c]) = v;
            }
        } else {
#pragma unroll
            for (int j = 0; j < TX_PER; ++j) {
                if (ocol0 + j < OW) op[j] = acc[j] + b;
            }
        }
    }
}

extern "C" void kernel_launch(void* const* d_in, const int* in_sizes, int n_in,
                              void* d_out, int out_size, void* d_ws, size_t ws_size,
                              hipStream_t stream)
{
    const float* X    = (const float*)d_in[0];
    const float* Wt   = (const float*)d_in[1];
    const float* Bias = (const float*)d_in[2];
    float* Out        = (float*)d_out;

    dim3 grid((OW + TILE_X - 1) / TILE_X,   // 32
              (OH + TILE_Y - 1) / TILE_Y);  // 128
    dim3 block(256);
    hipLaunchKernelGGL(conv2d_direct_f32, grid, block, 0, stream, X, Wt, Bias, Out);
}

// Round 2
// 98.731 us; speedup vs baseline: 1.2782x; 1.2782x over previous
//
#include <hip/hip_runtime.h>

#define H_IN 4096
#define W_IN 4096
#define KH 15
#define KW 15
#define OH (H_IN - KH + 1)   // 4082
#define OW (W_IN - KW + 1)   // 4082

#define TILE_X 128           // output tile width per block
#define TILE_Y 32            // output tile height per block
#define TX_PER 16            // outputs per thread along x
#define NTX (TILE_X / TX_PER)        // 8 threads in x
#define IN_H (TILE_Y + KH - 1)       // 46 input rows staged
#define L_CHUNKS 36                  // logical float4 chunks per row (144 >= 142 floats)
#define NQ 5                         // chunk-transpose minor dim ( ceil(36/8) )
#define ROW_DW 164                   // LDS row stride in dwords: 164%32==4 (bank entropy), %4==0 (16B align)
// physical chunk for logical chunk L:  (L&7)*NQ + (L>>3)  -> bank-group = (5*(L&7) + (L>>3) + row) mod 8
// For a row-octet (tx=0..7, chunk c): L=4tx+c covers 8 distinct bank groups -> conflict-free b128.

__global__ __launch_bounds__(256, 4)
void conv2d_direct_f32(const float* __restrict__ X,
                       const float* __restrict__ Wt,
                       const float* __restrict__ Bias,
                       float* __restrict__ Out)
{
    __shared__ float s_in[IN_H * ROW_DW];   // 46*164*4 = 30176 B

    const int tid = threadIdx.x;
    const int ox0 = blockIdx.x * TILE_X;
    const int oy0 = blockIdx.y * TILE_Y;

    // ---- stage input tile, chunk-transposed ----
    for (int i = tid; i < IN_H * L_CHUNKS; i += 256) {
        int r = i / L_CHUNKS;
        int L = i % L_CHUNKS;
        int gy = oy0 + r;       if (gy > H_IN - 1) gy = H_IN - 1;
        int gx = ox0 + L * 4;
        float4 v;
        if (gx + 3 < W_IN) {
            v = *reinterpret_cast<const float4*>(&X[(size_t)gy * W_IN + gx]);
        } else {
            const float* rp = &X[(size_t)gy * W_IN];
            v.x = rp[min(gx + 0, W_IN - 1)];
            v.y = rp[min(gx + 1, W_IN - 1)];
            v.z = rp[min(gx + 2, W_IN - 1)];
            v.w = rp[min(gx + 3, W_IN - 1)];
        }
        int phys = (L & 7) * NQ + (L >> 3);
        *reinterpret_cast<float4*>(&s_in[r * ROW_DW + phys * 4]) = v;
    }
    __syncthreads();

    const int tx = tid & (NTX - 1);     // 0..7
    const int ty = tid >> 3;            // 0..31

    // precompute the 8 swizzled byte offsets for this thread's window chunks
    int off[8];
#pragma unroll
    for (int c = 0; c < 8; ++c) {
        int L = 4 * tx + c;                       // logical chunk, <= 35
        off[c] = ((L & 7) * NQ + (L >> 3)) * 16;  // byte offset within row
    }

    float acc[TX_PER];
#pragma unroll
    for (int j = 0; j < TX_PER; ++j) acc[j] = 0.0f;

#pragma unroll 1
    for (int kh = 0; kh < KH; ++kh) {
        const char* rowp = reinterpret_cast<const char*>(s_in) + (size_t)(ty + kh) * (ROW_DW * 4);

        float win[32];
#pragma unroll
        for (int c = 0; c < 8; ++c) {
            float4 v = *reinterpret_cast<const float4*>(rowp + off[c]);
            win[4 * c + 0] = v.x;
            win[4 * c + 1] = v.y;
            win[4 * c + 2] = v.z;
            win[4 * c + 3] = v.w;
        }

        // weights: uniform global reads -> scalar K$ loads (broadcast, not LDS)
        const float* wrow = &Wt[kh * KW];
#pragma unroll
        for (int kw = 0; kw < KW; ++kw) {
            const float wv = wrow[kw];
#pragma unroll
            for (int j = 0; j < TX_PER; ++j) {
                acc[j] = fmaf(win[j + kw], wv, acc[j]);
            }
        }
    }

    // ---- store ----
    const float b = Bias[0];
    const int orow  = oy0 + ty;
    const int ocol0 = ox0 + tx * TX_PER;
    if (orow < OH) {
        float* op = &Out[(size_t)orow * OW + ocol0];
        if (ocol0 + TX_PER <= OW) {
#pragma unroll
            for (int c = 0; c < 8; ++c) {
                float2 v;
                v.x = acc[2 * c + 0] + b;
                v.y = acc[2 * c + 1] + b;
                *reinterpret_cast<float2*>(&op[2 * c]) = v;
            }
        } else {
#pragma unroll
            for (int j = 0; j < TX_PER; ++j) {
                if (ocol0 + j < OW) op[j] = acc[j] + b;
            }
        }
    }
}

extern "C" void kernel_launch(void* const* d_in, const int* in_sizes, int n_in,
                              void* d_out, int out_size, void* d_ws, size_t ws_size,
                              hipStream_t stream)
{
    const float* X    = (const float*)d_in[0];
    const float* Wt   = (const float*)d_in[1];
    const float* Bias = (const float*)d_in[2];
    float* Out        = (float*)d_out;

    dim3 grid((OW + TILE_X - 1) / TILE_X,   // 32
              (OH + TILE_Y - 1) / TILE_Y);  // 128
    dim3 block(256);
    hipLaunchKernelGGL(conv2d_direct_f32, grid, block, 0, stream, X, Wt, Bias, Out);
}

// Round 3
// 61.322 us; speedup vs baseline: 2.0580x; 1.6100x over previous
//
#include <hip/hip_runtime.h>

#define H_IN 4096
#define W_IN 4096
#define KH 15
#define KW 15
#define OH (H_IN - KH + 1)   // 4082
#define OW (W_IN - KW + 1)   // 4082

#define BM 64                // output rows per block
#define BN 64                // output cols per block
#define SROWS (BM + KH - 1)  // 78 staged rows
#define SCOLS 80             // staged bf16 cols per row (64 + 16 for k-window)
#define SSTR  88             // LDS row stride in bf16: 176 B, 176/16 = 11 (odd -> granule spread)

typedef __attribute__((ext_vector_type(8))) short short8;   // 8 bf16 (4 VGPRs) MFMA A/B frag
typedef __attribute__((ext_vector_type(4))) float f32x4;    // MFMA C/D frag

__device__ __forceinline__ ushort f2bf(float f) {
    union { float f; uint32_t u; } v; v.f = f;
    // round-to-nearest-even
    uint32_t r = (v.u + 0x7FFFu + ((v.u >> 16) & 1u)) >> 16;
    return (ushort)r;
}

__global__ __launch_bounds__(256, 2)
void conv2d_mfma_bf16(const float* __restrict__ X,
                      const float* __restrict__ Wt,
                      const float* __restrict__ Bias,
                      float* __restrict__ Out)
{
    __shared__ ushort s_x[SROWS * SSTR];      // 13728 B staged input (bf16)
    __shared__ ushort s_b[KH * 64 * 8];       // 15360 B banded weight frags [kh][lane][8]

    const int tid = threadIdx.x;
    const int ox0 = blockIdx.x * BN;
    const int oy0 = blockIdx.y * BM;

    // ---- build banded Toeplitz weight fragments: B[k][j] = w[kh][k-j] ----
    // frag layout for mfma_16x16x32: lane l holds B[8*(l>>4)+t][l&15], t=0..7
    for (int idx = tid; idx < KH * 64; idx += 256) {
        int kh = idx >> 6;
        int l  = idx & 63;
        int j  = l & 15;
        int k0 = (l >> 4) * 8;
        ushort* dst = &s_b[idx * 8];
#pragma unroll
        for (int t = 0; t < 8; ++t) {
            int kw = k0 + t - j;
            float wv = (kw >= 0 && kw < KW) ? Wt[kh * KW + kw] : 0.0f;
            dst[t] = f2bf(wv);
        }
    }

    // ---- stage X tile (fp32 -> bf16), clamped at edges ----
    const bool interior = (ox0 + SCOLS <= W_IN);
    for (int i = tid; i < SROWS * (SCOLS / 4); i += 256) {
        int r  = i / (SCOLS / 4);
        int c4 = i % (SCOLS / 4);
        int gy = oy0 + r; if (gy > H_IN - 1) gy = H_IN - 1;
        const float* rp = &X[(size_t)gy * W_IN];
        int gx = ox0 + c4 * 4;
        float4 v;
        if (interior) {
            v = *reinterpret_cast<const float4*>(&rp[gx]);
        } else {
            v.x = rp[min(gx + 0, W_IN - 1)];
            v.y = rp[min(gx + 1, W_IN - 1)];
            v.z = rp[min(gx + 2, W_IN - 1)];
            v.w = rp[min(gx + 3, W_IN - 1)];
        }
        uint32_t p0 = (uint32_t)f2bf(v.x) | ((uint32_t)f2bf(v.y) << 16);
        uint32_t p1 = (uint32_t)f2bf(v.z) | ((uint32_t)f2bf(v.w) << 16);
        uint2 pk; pk.x = p0; pk.y = p1;
        *reinterpret_cast<uint2*>(&s_x[r * SSTR + c4 * 4]) = pk;
    }
    __syncthreads();

    const int l = tid & 63;          // lane
    const int w = tid >> 6;          // wave 0..3 -> output row band oy0+16w

    // hoist the 15 B-frags to registers (kh loop fully unrolled -> static idx)
    short8 bfr[KH];
#pragma unroll
    for (int kh = 0; kh < KH; ++kh)
        bfr[kh] = *reinterpret_cast<const short8*>(&s_b[(kh * 64 + l) * 8]);

    f32x4 acc[4];
#pragma unroll
    for (int j = 0; j < 4; ++j) acc[j] = (f32x4){0.f, 0.f, 0.f, 0.f};

    // A frag: lane l holds A[l&15][8*(l>>4)+t]; A[i][k] = X_tile[16w + i + kh][16j + k]
    const ushort* abase = &s_x[(w * 16 + (l & 15)) * SSTR + (l >> 4) * 8];

#pragma unroll
    for (int kh = 0; kh < KH; ++kh) {
#pragma unroll
        for (int j = 0; j < 4; ++j) {
            short8 a = *reinterpret_cast<const short8*>(abase + kh * SSTR + j * 16);
            acc[j] = __builtin_amdgcn_mfma_f32_16x16x32_bf16(a, bfr[kh], acc[j], 0, 0, 0);
        }
    }

    // ---- store: C/D layout col=lane&15, row=(lane>>4)*4+r (verified m89) ----
    const float b = Bias[0];
    const int orow0 = oy0 + w * 16 + (l >> 4) * 4;
    const int ocol  = ox0 + (l & 15);
#pragma unroll
    for (int j = 0; j < 4; ++j) {
        int oc = ocol + j * 16;
        if (oc < OW) {
#pragma unroll
            for (int r = 0; r < 4; ++r) {
                int orow = orow0 + r;
                if (orow < OH)
                    Out[(size_t)orow * OW + oc] = acc[j][r] + b;
            }
        }
    }
}

extern "C" void kernel_launch(void* const* d_in, const int* in_sizes, int n_in,
                              void* d_out, int out_size, void* d_ws, size_t ws_size,
                              hipStream_t stream)
{
    const float* X    = (const float*)d_in[0];
    const float* Wt   = (const float*)d_in[1];
    const float* Bias = (const float*)d_in[2];
    float* Out        = (float*)d_out;

    dim3 grid((OW + BN - 1) / BN,    // 64
              (OH + BM - 1) / BM);   // 64
    dim3 block(256);
    hipLaunchKernelGGL(conv2d_mfma_bf16, grid, block, 0, stream, X, Wt, Bias, Out);
}

// Round 4
// 51.838 us; speedup vs baseline: 2.4345x; 1.1830x over previous
//
#include <hip/hip_runtime.h>

#define H_IN 4096
#define W_IN 4096
#define KH 15
#define KW 15
#define OH (H_IN - KH + 1)   // 4082
#define OW (W_IN - KW + 1)   // 4082

#define BM 64                // output rows per block
#define BN 128               // output cols per block (8 j-tiles of 16)
#define NJ (BN / 16)         // 8
#define SROWS (BM + KH - 1)  // 78 staged rows
#define SCOLS 144            // staged bf16 cols per row (128 + 16 window)
#define SSTR  160            // LDS row stride in bf16 = 20 granules of 16B:
                             // granule(l) = 20*(l&15) + 2j + (l>>4) -> exactly 2 lanes
                             // per granule-class (2-way = free, m136)

// union LDS: X tile (78*160 ushort = 24960B) overlaps weight-frag build (15*64*8 = 7680)
#define S_ELEMS (SROWS * SSTR)

typedef __attribute__((ext_vector_type(8))) short short8;   // MFMA A/B frag (8 bf16)
typedef __attribute__((ext_vector_type(4))) float f32x4;    // MFMA C/D frag

__device__ __forceinline__ ushort f2bf(float f) {
    union { float f; uint32_t u; } v; v.f = f;
    uint32_t r = (v.u + 0x7FFFu + ((v.u >> 16) & 1u)) >> 16;  // RNE
    return (ushort)r;
}

__global__ __launch_bounds__(256, 2)
void conv2d_mfma_bf16(const float* __restrict__ X,
                      const float* __restrict__ Wt,
                      const float* __restrict__ Bias,
                      float* __restrict__ Out)
{
    __shared__ ushort s_u[S_ELEMS];

    const int tid = threadIdx.x;
    const int ox0 = blockIdx.x * BN;
    const int oy0 = blockIdx.y * BM;
    const int l = tid & 63;          // lane
    const int w = tid >> 6;          // wave 0..3 -> row band oy0 + 16w

    // ---- phase 1: build banded Toeplitz weight frags in LDS ----
    // B[k][j] = w[kh][k-j]; frag: lane l holds B[8*(l>>4)+t][l&15], t=0..7
    for (int idx = tid; idx < KH * 64; idx += 256) {
        int kh = idx >> 6;
        int ll = idx & 63;
        int j  = ll & 15;
        int k0 = (ll >> 4) * 8;
        ushort* dst = &s_u[idx * 8];
#pragma unroll
        for (int t = 0; t < 8; ++t) {
            int kw = k0 + t - j;
            float wv = (kw >= 0 && kw < KW) ? Wt[kh * KW + kw] : 0.0f;
            dst[t] = f2bf(wv);
        }
    }
    __syncthreads();

    // hoist 15 B-frags to registers (static idx, kh fully unrolled later)
    short8 bfr[KH];
#pragma unroll
    for (int kh = 0; kh < KH; ++kh)
        bfr[kh] = *reinterpret_cast<const short8*>(&s_u[(kh * 64 + l) * 8]);
    __syncthreads();   // all frag reads done before X overwrites the region

    // ---- phase 2: stage X tile (fp32 -> bf16), clamped at edges ----
    const bool interior = (ox0 + SCOLS <= W_IN);
    for (int i = tid; i < SROWS * (SCOLS / 4); i += 256) {
        int r  = i / (SCOLS / 4);
        int c4 = i % (SCOLS / 4);
        int gy = oy0 + r; if (gy > H_IN - 1) gy = H_IN - 1;
        const float* rp = &X[(size_t)gy * W_IN];
        int gx = ox0 + c4 * 4;
        float4 v;
        if (interior) {
            v = *reinterpret_cast<const float4*>(&rp[gx]);
        } else {
            v.x = rp[min(gx + 0, W_IN - 1)];
            v.y = rp[min(gx + 1, W_IN - 1)];
            v.z = rp[min(gx + 2, W_IN - 1)];
            v.w = rp[min(gx + 3, W_IN - 1)];
        }
        uint2 pk;
        pk.x = (uint32_t)f2bf(v.x) | ((uint32_t)f2bf(v.y) << 16);
        pk.y = (uint32_t)f2bf(v.z) | ((uint32_t)f2bf(v.w) << 16);
        *reinterpret_cast<uint2*>(&s_u[r * SSTR + c4 * 4]) = pk;
    }
    __syncthreads();

    // ---- phase 3: MFMA main loop ----
    f32x4 acc[NJ];
#pragma unroll
    for (int j = 0; j < NJ; ++j) acc[j] = (f32x4){0.f, 0.f, 0.f, 0.f};

    // A[i][k] = X_tile[16w + i + kh][16j + k]; lane l: A[l&15][8*(l>>4)+t]
    const ushort* abase = &s_u[(w * 16 + (l & 15)) * SSTR + (l >> 4) * 8];

#pragma unroll
    for (int kh = 0; kh < KH; ++kh) {
        const ushort* arow = abase + kh * SSTR;
#pragma unroll
        for (int j = 0; j < NJ; ++j) {
            short8 a = *reinterpret_cast<const short8*>(arow + j * 16);
            acc[j] = __builtin_amdgcn_mfma_f32_16x16x32_bf16(a, bfr[kh], acc[j], 0, 0, 0);
        }
    }

    // ---- store: C/D layout col=lane&15, row=(lane>>4)*4+r ----
    const float b = Bias[0];
    const int orow0 = oy0 + w * 16 + (l >> 4) * 4;
    const int ocol  = ox0 + (l & 15);
#pragma unroll
    for (int j = 0; j < NJ; ++j) {
        int oc = ocol + j * 16;
        if (oc < OW) {
#pragma unroll
            for (int r = 0; r < 4; ++r) {
                int orow = orow0 + r;
                if (orow < OH)
                    Out[(size_t)orow * OW + oc] = acc[j][r] + b;
            }
        }
    }
}

extern "C" void kernel_launch(void* const* d_in, const int* in_sizes, int n_in,
                              void* d_out, int out_size, void* d_ws, size_t ws_size,
                              hipStream_t stream)
{
    const float* X    = (const float*)d_in[0];
    const float* Wt   = (const float*)d_in[1];
    const float* Bias = (const float*)d_in[2];
    float* Out        = (float*)d_out;

    dim3 grid((OW + BN - 1) / BN,    // 32
              (OH + BM - 1) / BM);   // 64
    dim3 block(256);
    hipLaunchKernelGGL(conv2d_mfma_bf16, grid, block, 0, stream, X, Wt, Bias, Out);
}